// Round 1
// baseline (981.828 us; speedup 1.0000x reference)
//
#include <hip/hip_runtime.h>
#include <hip/hip_bf16.h>

// ---------------------------------------------------------------------------
// PLTBlock: out = (x Wq^T)( (x Wk^T)^T (x Wv^T) ) Wp^T + bp + x   (linear attn)
// B=8, S=4096, D=1024.  All heavy math in bf16 MFMA (16x16x32), fp32 accum.
// ---------------------------------------------------------------------------

#define B_DIM 8
#define S_DIM 4096
#define D_DIM 1024
#define M_TOT (B_DIM * S_DIM)   // 32768

using short8 = __attribute__((ext_vector_type(8))) short;
using f32x4  = __attribute__((ext_vector_type(4))) float;

#define TILE_M 128
#define TILE_N 128
#define TILE_K 32

__device__ __forceinline__ void g2l16(const void* g, void* l) {
  __builtin_amdgcn_global_load_lds(
      (const __attribute__((address_space(1))) unsigned int*)g,
      (__attribute__((address_space(3))) unsigned int*)l, 16, 0, 0);
}

__device__ __forceinline__ unsigned short f2b(float f) {
  __hip_bfloat16 h = __float2bfloat16(f);
  return __builtin_bit_cast(unsigned short, h);
}

// C[m,n] = sum_k A[m,k] * Bt[n,k]   (A: MxK row-major, Bt: NxK row-major)
// FINAL=false: C is bf16. FINAL=true: C is fp32, += bias[n] + resid[m*ldc+n].
template<bool FINAL>
__global__ __launch_bounds__(256)
void gemm_bt(const unsigned short* __restrict__ A,
             const unsigned short* __restrict__ Bt,
             void* __restrict__ C,
             int K, int lda, int ldb, int ldc,
             long long sA, long long sB, long long sC,
             const float* __restrict__ bias,
             const float* __restrict__ resid)
{
  __shared__ __align__(16) unsigned short As[TILE_M * TILE_K];
  __shared__ __align__(16) unsigned short Bs[TILE_N * TILE_K];

  const int tid  = threadIdx.x;
  const int wave = tid >> 6;       // 0..3
  const int lane = tid & 63;
  const int qd   = lane >> 4;      // quad 0..3
  const int ln   = lane & 15;
  const int wr   = (wave >> 1) * 64;   // wave row offset within 128x128 tile
  const int wc   = (wave & 1) * 64;    // wave col offset
  const long long m0 = (long long)blockIdx.y * TILE_M;
  const long long n0 = (long long)blockIdx.x * TILE_N;
  const int bz = blockIdx.z;

  const unsigned short* Ab = A  + (long long)bz * sA;
  const unsigned short* Bb = Bt + (long long)bz * sB;

  // Staging: 128x32 bf16 tile = 8192B = 512 x 16B chunks; 256 threads x 2 iters.
  // chunk g: LDS ushort offset g*8; row g>>2, col-chunk (g&3)*8.
  // LDS dst must be wave-uniform base + lane*16 (global_load_lds semantics).
  const int r0 = tid >> 2;                 // rows 0..63
  const int c0 = (tid & 3) * 8;
  const int r1 = (256 + tid) >> 2;         // rows 64..127
  const int c1 = (tid & 3) * 8;
  unsigned short* lpA0 = As + wave * 512;            // (wave*64)*8
  unsigned short* lpA1 = As + 2048 + wave * 512;     // (256+wave*64)*8
  unsigned short* lpB0 = Bs + wave * 512;
  unsigned short* lpB1 = Bs + 2048 + wave * 512;

  f32x4 acc[4][4];
#pragma unroll
  for (int i = 0; i < 4; ++i)
#pragma unroll
    for (int j = 0; j < 4; ++j)
      acc[i][j] = (f32x4){0.f, 0.f, 0.f, 0.f};

  for (int k0 = 0; k0 < K; k0 += TILE_K) {
    g2l16(Ab + (m0 + r0) * lda + k0 + c0, lpA0);
    g2l16(Ab + (m0 + r1) * lda + k0 + c1, lpA1);
    g2l16(Bb + (n0 + r0) * ldb + k0 + c0, lpB0);
    g2l16(Bb + (n0 + r1) * ldb + k0 + c1, lpB1);
    __syncthreads();   // compiler emits s_waitcnt vmcnt(0) before s_barrier

    short8 af[4], bf[4];
#pragma unroll
    for (int i = 0; i < 4; ++i)
      af[i] = *(const short8*)(As + (wr + i * 16 + ln) * TILE_K + qd * 8);
#pragma unroll
    for (int j = 0; j < 4; ++j)
      bf[j] = *(const short8*)(Bs + (wc + j * 16 + ln) * TILE_K + qd * 8);

#pragma unroll
    for (int i = 0; i < 4; ++i)
#pragma unroll
      for (int j = 0; j < 4; ++j)
        acc[i][j] = __builtin_amdgcn_mfma_f32_16x16x32_bf16(af[i], bf[j], acc[i][j], 0, 0, 0);

    __syncthreads();
  }

  // Epilogue. C/D layout (verified m89): col = lane&15, row = (lane>>4)*4 + reg.
  if constexpr (FINAL) {
    float* Cf = (float*)C + (long long)bz * sC;
#pragma unroll
    for (int i = 0; i < 4; ++i)
#pragma unroll
      for (int j = 0; j < 4; ++j)
#pragma unroll
        for (int r = 0; r < 4; ++r) {
          long long row = m0 + wr + i * 16 + qd * 4 + r;
          long long col = n0 + wc + j * 16 + ln;
          Cf[row * ldc + col] = acc[i][j][r] + bias[col] + resid[row * ldc + col];
        }
  } else {
    __hip_bfloat16* Cb = (__hip_bfloat16*)C + (long long)bz * sC;
#pragma unroll
    for (int i = 0; i < 4; ++i)
#pragma unroll
      for (int j = 0; j < 4; ++j)
#pragma unroll
        for (int r = 0; r < 4; ++r) {
          long long row = m0 + wr + i * 16 + qd * 4 + r;
          long long col = n0 + wc + j * 16 + ln;
          Cb[row * ldc + col] = __float2bfloat16(acc[i][j][r]);
        }
  }
}

// dst[b][e][s] = src[b*S + s][e]   (src: [B*S, D] bf16, dst: [B, D, S] bf16)
__global__ __launch_bounds__(256)
void transpose_bds(const unsigned short* __restrict__ src,
                   unsigned short* __restrict__ dst)
{
  __shared__ unsigned short tile[64][68];   // +4 pad breaks bank alignment
  const int b  = blockIdx.z;
  const int s0 = blockIdx.x * 64;
  const int e0 = blockIdx.y * 64;
  const int tx = threadIdx.x & 15;
  const int ty = threadIdx.x >> 4;

#pragma unroll
  for (int r = 0; r < 4; ++r) {
    int s = ty * 4 + r;
    ushort4 d = *(const ushort4*)(src + ((size_t)b * S_DIM + s0 + s) * D_DIM + e0 + tx * 4);
    *(ushort4*)&tile[s][tx * 4] = d;
  }
  __syncthreads();
#pragma unroll
  for (int r = 0; r < 4; ++r) {
    int e = ty * 4 + r;
    ushort4 d;
    d.x = tile[tx * 4 + 0][e];
    d.y = tile[tx * 4 + 1][e];
    d.z = tile[tx * 4 + 2][e];
    d.w = tile[tx * 4 + 3][e];
    *(ushort4*)(dst + ((size_t)b * D_DIM + e0 + e) * S_DIM + s0 + tx * 4) = d;
  }
}

__global__ __launch_bounds__(256)
void cast_f32_bf16(const float* __restrict__ src, unsigned short* __restrict__ dst, int n4)
{
  int i = blockIdx.x * 256 + threadIdx.x;
  if (i >= n4) return;
  float4 f = ((const float4*)src)[i];
  ushort4 u;
  u.x = f2b(f.x); u.y = f2b(f.y); u.z = f2b(f.z); u.w = f2b(f.w);
  ((ushort4*)dst)[i] = u;
}

extern "C" void kernel_launch(void* const* d_in, const int* in_sizes, int n_in,
                              void* d_out, int out_size, void* d_ws, size_t ws_size,
                              hipStream_t stream) {
  const float* x  = (const float*)d_in[0];
  const float* Wq = (const float*)d_in[1];
  const float* Wk = (const float*)d_in[2];
  const float* Wv = (const float*)d_in[3];
  const float* Wp = (const float*)d_in[4];
  const float* bp = (const float*)d_in[5];
  float* out = (float*)d_out;
  char* ws = (char*)d_ws;

  // Workspace layout (bytes). Peak 264 MiB with reuse.
  // [0,64M): xb  -> later kT -> later zb
  // [64M,72M): Wq/Wk/Wv/Wp bf16 (2 MiB each)
  // [72M,136M): q
  // [136M,200M): k -> later vT
  // [200M,264M): v ; kvT at [200M,216M) after v dead
  unsigned short* xb  = (unsigned short*)(ws + 0);
  unsigned short* Wqb = (unsigned short*)(ws + 67108864);
  unsigned short* Wkb = (unsigned short*)(ws + 69206016);
  unsigned short* Wvb = (unsigned short*)(ws + 71303168);
  unsigned short* Wpb = (unsigned short*)(ws + 73400320);
  unsigned short* qb  = (unsigned short*)(ws + 75497472);
  unsigned short* kb  = (unsigned short*)(ws + 142606336);
  unsigned short* vb  = (unsigned short*)(ws + 209715200);
  unsigned short* kT  = (unsigned short*)(ws + 0);          // reuse xb
  unsigned short* vT  = (unsigned short*)(ws + 142606336);  // reuse kb
  unsigned short* kvT = (unsigned short*)(ws + 209715200);  // reuse vb
  unsigned short* zb  = (unsigned short*)(ws + 0);          // reuse kT

  // ---- casts to bf16 ----
  cast_f32_bf16<<<dim3(M_TOT * D_DIM / 4 / 256), 256, 0, stream>>>(x, xb, M_TOT * D_DIM / 4);
  cast_f32_bf16<<<dim3(D_DIM * D_DIM / 4 / 256), 256, 0, stream>>>(Wq, Wqb, D_DIM * D_DIM / 4);
  cast_f32_bf16<<<dim3(D_DIM * D_DIM / 4 / 256), 256, 0, stream>>>(Wk, Wkb, D_DIM * D_DIM / 4);
  cast_f32_bf16<<<dim3(D_DIM * D_DIM / 4 / 256), 256, 0, stream>>>(Wv, Wvb, D_DIM * D_DIM / 4);
  cast_f32_bf16<<<dim3(D_DIM * D_DIM / 4 / 256), 256, 0, stream>>>(Wp, Wpb, D_DIM * D_DIM / 4);

  // ---- q,k,v = x @ W^T : M=32768, N=1024, K=1024 ----
  dim3 gqkv(D_DIM / TILE_N, M_TOT / TILE_M, 1);
  gemm_bt<false><<<gqkv, 256, 0, stream>>>(xb, Wqb, qb, D_DIM, D_DIM, D_DIM, D_DIM, 0, 0, 0, nullptr, nullptr);
  gemm_bt<false><<<gqkv, 256, 0, stream>>>(xb, Wkb, kb, D_DIM, D_DIM, D_DIM, D_DIM, 0, 0, 0, nullptr, nullptr);
  gemm_bt<false><<<gqkv, 256, 0, stream>>>(xb, Wvb, vb, D_DIM, D_DIM, D_DIM, D_DIM, 0, 0, 0, nullptr, nullptr);

  // ---- kT[b][e][s], vT[b][f][s] ----
  dim3 gt(S_DIM / 64, D_DIM / 64, B_DIM);
  transpose_bds<<<gt, 256, 0, stream>>>(kb, kT);
  transpose_bds<<<gt, 256, 0, stream>>>(vb, vT);

  // ---- kvT[b][f][e] = sum_s vT[f,s] * kT[e,s] : M=N=1024, K=4096, batched ----
  dim3 gkv(D_DIM / TILE_N, D_DIM / TILE_M, B_DIM);
  gemm_bt<false><<<gkv, 256, 0, stream>>>(vT, kT, kvT, S_DIM, S_DIM, S_DIM, D_DIM,
                                          (long long)D_DIM * S_DIM, (long long)D_DIM * S_DIM,
                                          (long long)D_DIM * D_DIM, nullptr, nullptr);

  // ---- z[b][s][f] = sum_e q[s,e] * kvT[f,e] : M=4096, N=1024, K=1024, batched ----
  dim3 gz(D_DIM / TILE_N, S_DIM / TILE_M, B_DIM);
  gemm_bt<false><<<gz, 256, 0, stream>>>(qb, kvT, zb, D_DIM, D_DIM, D_DIM, D_DIM,
                                         (long long)S_DIM * D_DIM, (long long)D_DIM * D_DIM,
                                         (long long)S_DIM * D_DIM, nullptr, nullptr);

  // ---- out = z @ Wp^T + bp + x : M=32768, N=1024, K=1024, fp32 out ----
  gemm_bt<true><<<gqkv, 256, 0, stream>>>(zb, Wpb, out, D_DIM, D_DIM, D_DIM, D_DIM,
                                          0, 0, 0, bp, x);
  (void)in_sizes; (void)n_in; (void)out_size; (void)ws_size;
}

// Round 2
// 807.979 us; speedup vs baseline: 1.2152x; 1.2152x over previous
//
#include <hip/hip_runtime.h>
#include <hip/hip_bf16.h>

// ---------------------------------------------------------------------------
// PLTBlock: out = (x Wq^T)( (x Wk^T)^T (x Wv^T) ) Wp^T + bp + x   (linear attn)
// B=8, S=4096, D=1024.  bf16 MFMA 16x16x32, fp32 accum.
// R2: BK=64 (half the barrier drains), XCD-stripe swizzle (A/B hot in per-XCD
//     L2), row-rotated LDS chunk layout (kills BK=64 bank conflicts while
//     keeping global_load_lds's wave-uniform-base+lane*16 constraint).
// ---------------------------------------------------------------------------

#define B_DIM 8
#define S_DIM 4096
#define D_DIM 1024
#define M_TOT (B_DIM * S_DIM)   // 32768

using short8 = __attribute__((ext_vector_type(8))) short;
using f32x4  = __attribute__((ext_vector_type(4))) float;

#define TILE_M 128
#define TILE_N 128
#define TILE_K 64

__device__ __forceinline__ void g2l16(const void* g, void* l) {
  __builtin_amdgcn_global_load_lds(
      (const __attribute__((address_space(1))) unsigned int*)g,
      (__attribute__((address_space(3))) unsigned int*)l, 16, 0, 0);
}

__device__ __forceinline__ unsigned short f2b(float f) {
  __hip_bfloat16 h = __float2bfloat16(f);
  return __builtin_bit_cast(unsigned short, h);
}

// C[m,n] = sum_k A[m,k] * Bt[n,k]   (A: MxK row-major, Bt: NxK row-major)
// FINAL=false: C bf16.  FINAL=true: C fp32, += bias[n] + resid[m*ldc+n].
//
// LDS layout (per 128x64 tile, row-major rows of 64 ushorts): the 8 16B
// column-chunks of row r are stored ROTATED: LDS slot c holds global chunk
// (c + r) & 7. Staging thread t therefore loads global chunk
// ((t&7)+(t>>3))&7 of its row; fragment reads index slot (cg - row)&7.
// Net effect: ds_read_b128 fragment fetches spread across all banks (2-way
// residual aliasing only), while global_load_lds keeps its mandatory
// base + lane*16 contiguous destination.
template<bool FINAL>
__global__ __launch_bounds__(256)
void gemm_bt(const unsigned short* __restrict__ A,
             const unsigned short* __restrict__ Bt,
             void* __restrict__ C,
             int K, int lda, int ldb, int ldc,
             long long sA, long long sB, long long sC,
             const float* __restrict__ bias,
             const float* __restrict__ resid)
{
  __shared__ __align__(16) unsigned short As[TILE_M * TILE_K];  // 16 KiB
  __shared__ __align__(16) unsigned short Bs[TILE_N * TILE_K];  // 16 KiB

  const int tid  = threadIdx.x;
  const int wave = tid >> 6;
  const int lane = tid & 63;
  const int qd   = lane >> 4;
  const int ln   = lane & 15;
  const int wr   = (wave >> 1) * 64;
  const int wc   = (wave & 1) * 64;

  // XCD-stripe swizzle: xcd ~ flat%8 (round-robin dispatch). Give XCD s a
  // contiguous by-stripe of gridDim.y/8 row-tiles, x-inner, so its resident
  // blocks share A row-tiles and the whole B panel in its private L2.
  const int flat = blockIdx.y * gridDim.x + blockIdx.x;
  const int s    = flat & 7;
  const int t8   = flat >> 3;
  const int bx   = t8 % gridDim.x;
  const int by   = s * (gridDim.y >> 3) + t8 / gridDim.x;

  const long long m0 = (long long)by * TILE_M;
  const long long n0 = (long long)bx * TILE_N;
  const int bz = blockIdx.z;

  const unsigned short* Ab = A  + (long long)bz * sA;
  const unsigned short* Bb = Bt + (long long)bz * sB;

  // Staging: 128x64 bf16 = 16 KiB = 1024 16B-chunks; 256 thr x 4 iters.
  // Thread t, iter it: row (t>>3)+32*it, global col-chunk ((t&7)+(t>>3))&7.
  const int srow = tid >> 3;
  const int scg  = ((tid & 7) + (tid >> 3)) & 7;
  const unsigned short* pA = Ab + (m0 + srow) * lda + scg * 8;
  const unsigned short* pB = Bb + (n0 + srow) * ldb + scg * 8;
  const long long rsA = 32LL * lda, rsB = 32LL * ldb;
  unsigned short* lA = As + wave * 512;   // + it*2048
  unsigned short* lB = Bs + wave * 512;

  // Fragment LDS offsets (ushort units), hoisted: row ri, chunk cg=kk*4+qd.
  int offA[2][4], offB[2][4];
#pragma unroll
  for (int kk = 0; kk < 2; ++kk)
#pragma unroll
    for (int i = 0; i < 4; ++i) {
      int ra = wr + i * 16 + ln;
      int rb = wc + i * 16 + ln;
      int cg = kk * 4 + qd;
      offA[kk][i] = ra * 64 + (((cg - ra) & 7) * 8);
      offB[kk][i] = rb * 64 + (((cg - rb) & 7) * 8);
    }

  f32x4 acc[4][4];
#pragma unroll
  for (int i = 0; i < 4; ++i)
#pragma unroll
    for (int j = 0; j < 4; ++j)
      acc[i][j] = (f32x4){0.f, 0.f, 0.f, 0.f};

  for (int k0 = 0; k0 < K; k0 += TILE_K) {
#pragma unroll
    for (int it = 0; it < 4; ++it) g2l16(pA + it * rsA, lA + it * 2048);
#pragma unroll
    for (int it = 0; it < 4; ++it) g2l16(pB + it * rsB, lB + it * 2048);
    __syncthreads();

#pragma unroll
    for (int kk = 0; kk < 2; ++kk) {
      short8 af[4], bf[4];
#pragma unroll
      for (int i = 0; i < 4; ++i) af[i] = *(const short8*)(As + offA[kk][i]);
#pragma unroll
      for (int j = 0; j < 4; ++j) bf[j] = *(const short8*)(Bs + offB[kk][j]);
#pragma unroll
      for (int i = 0; i < 4; ++i)
#pragma unroll
        for (int j = 0; j < 4; ++j)
          acc[i][j] = __builtin_amdgcn_mfma_f32_16x16x32_bf16(af[i], bf[j], acc[i][j], 0, 0, 0);
    }
    __syncthreads();
    pA += TILE_K; pB += TILE_K;
  }

  // Epilogue. C/D layout (m89): col = lane&15, row = (lane>>4)*4 + reg.
  if constexpr (FINAL) {
    float* Cf = (float*)C + (long long)bz * sC;
#pragma unroll
    for (int i = 0; i < 4; ++i)
#pragma unroll
      for (int j = 0; j < 4; ++j)
#pragma unroll
        for (int r = 0; r < 4; ++r) {
          long long row = m0 + wr + i * 16 + qd * 4 + r;
          long long col = n0 + wc + j * 16 + ln;
          Cf[row * ldc + col] = acc[i][j][r] + bias[col] + resid[row * ldc + col];
        }
  } else {
    __hip_bfloat16* Cb = (__hip_bfloat16*)C + (long long)bz * sC;
#pragma unroll
    for (int i = 0; i < 4; ++i)
#pragma unroll
      for (int j = 0; j < 4; ++j)
#pragma unroll
        for (int r = 0; r < 4; ++r) {
          long long row = m0 + wr + i * 16 + qd * 4 + r;
          long long col = n0 + wc + j * 16 + ln;
          Cb[row * ldc + col] = __float2bfloat16(acc[i][j][r]);
        }
  }
}

// dst[b][e][s] = src[b*S + s][e]   (src: [B*S, D] bf16, dst: [B, D, S] bf16)
__global__ __launch_bounds__(256)
void transpose_bds(const unsigned short* __restrict__ src,
                   unsigned short* __restrict__ dst)
{
  __shared__ unsigned short tile[64][68];
  const int b  = blockIdx.z;
  const int s0 = blockIdx.x * 64;
  const int e0 = blockIdx.y * 64;
  const int tx = threadIdx.x & 15;
  const int ty = threadIdx.x >> 4;

#pragma unroll
  for (int r = 0; r < 4; ++r) {
    int s = ty * 4 + r;
    ushort4 d = *(const ushort4*)(src + ((size_t)b * S_DIM + s0 + s) * D_DIM + e0 + tx * 4);
    *(ushort4*)&tile[s][tx * 4] = d;
  }
  __syncthreads();
#pragma unroll
  for (int r = 0; r < 4; ++r) {
    int e = ty * 4 + r;
    ushort4 d;
    d.x = tile[tx * 4 + 0][e];
    d.y = tile[tx * 4 + 1][e];
    d.z = tile[tx * 4 + 2][e];
    d.w = tile[tx * 4 + 3][e];
    *(ushort4*)(dst + ((size_t)b * D_DIM + e0 + e) * S_DIM + s0 + tx * 4) = d;
  }
}

__global__ __launch_bounds__(256)
void cast_f32_bf16(const float* __restrict__ src, unsigned short* __restrict__ dst, int n4)
{
  int i = blockIdx.x * 256 + threadIdx.x;
  if (i >= n4) return;
  float4 f = ((const float4*)src)[i];
  ushort4 u;
  u.x = f2b(f.x); u.y = f2b(f.y); u.z = f2b(f.z); u.w = f2b(f.w);
  ((ushort4*)dst)[i] = u;
}

extern "C" void kernel_launch(void* const* d_in, const int* in_sizes, int n_in,
                              void* d_out, int out_size, void* d_ws, size_t ws_size,
                              hipStream_t stream) {
  const float* x  = (const float*)d_in[0];
  const float* Wq = (const float*)d_in[1];
  const float* Wk = (const float*)d_in[2];
  const float* Wv = (const float*)d_in[3];
  const float* Wp = (const float*)d_in[4];
  const float* bp = (const float*)d_in[5];
  float* out = (float*)d_out;
  char* ws = (char*)d_ws;

  unsigned short* xb  = (unsigned short*)(ws + 0);
  unsigned short* Wqb = (unsigned short*)(ws + 67108864);
  unsigned short* Wkb = (unsigned short*)(ws + 69206016);
  unsigned short* Wvb = (unsigned short*)(ws + 71303168);
  unsigned short* Wpb = (unsigned short*)(ws + 73400320);
  unsigned short* qb  = (unsigned short*)(ws + 75497472);
  unsigned short* kb  = (unsigned short*)(ws + 142606336);
  unsigned short* vb  = (unsigned short*)(ws + 209715200);
  unsigned short* kT  = (unsigned short*)(ws + 0);          // reuse xb
  unsigned short* vT  = (unsigned short*)(ws + 142606336);  // reuse kb
  unsigned short* kvT = (unsigned short*)(ws + 209715200);  // reuse vb
  unsigned short* zb  = (unsigned short*)(ws + 0);          // reuse kT

  // ---- casts to bf16 ----
  cast_f32_bf16<<<dim3(M_TOT * D_DIM / 4 / 256), 256, 0, stream>>>(x, xb, M_TOT * D_DIM / 4);
  cast_f32_bf16<<<dim3(D_DIM * D_DIM / 4 / 256), 256, 0, stream>>>(Wq, Wqb, D_DIM * D_DIM / 4);
  cast_f32_bf16<<<dim3(D_DIM * D_DIM / 4 / 256), 256, 0, stream>>>(Wk, Wkb, D_DIM * D_DIM / 4);
  cast_f32_bf16<<<dim3(D_DIM * D_DIM / 4 / 256), 256, 0, stream>>>(Wv, Wvb, D_DIM * D_DIM / 4);
  cast_f32_bf16<<<dim3(D_DIM * D_DIM / 4 / 256), 256, 0, stream>>>(Wp, Wpb, D_DIM * D_DIM / 4);

  // ---- q,k,v = x @ W^T : M=32768, N=1024, K=1024 ----
  dim3 gqkv(D_DIM / TILE_N, M_TOT / TILE_M, 1);
  gemm_bt<false><<<gqkv, 256, 0, stream>>>(xb, Wqb, qb, D_DIM, D_DIM, D_DIM, D_DIM, 0, 0, 0, nullptr, nullptr);
  gemm_bt<false><<<gqkv, 256, 0, stream>>>(xb, Wkb, kb, D_DIM, D_DIM, D_DIM, D_DIM, 0, 0, 0, nullptr, nullptr);
  gemm_bt<false><<<gqkv, 256, 0, stream>>>(xb, Wvb, vb, D_DIM, D_DIM, D_DIM, D_DIM, 0, 0, 0, nullptr, nullptr);

  // ---- kT[b][e][s], vT[b][f][s] ----
  dim3 gt(S_DIM / 64, D_DIM / 64, B_DIM);
  transpose_bds<<<gt, 256, 0, stream>>>(kb, kT);
  transpose_bds<<<gt, 256, 0, stream>>>(vb, vT);

  // ---- kvT[b][f][e] = sum_s vT[f,s] * kT[e,s] : M=N=1024, K=4096 ----
  dim3 gkv(D_DIM / TILE_N, D_DIM / TILE_M, B_DIM);
  gemm_bt<false><<<gkv, 256, 0, stream>>>(vT, kT, kvT, S_DIM, S_DIM, S_DIM, D_DIM,
                                          (long long)D_DIM * S_DIM, (long long)D_DIM * S_DIM,
                                          (long long)D_DIM * D_DIM, nullptr, nullptr);

  // ---- z[b][s][f] = sum_e q[s,e] * kvT[f,e] : M=4096, N=1024, K=1024 ----
  dim3 gz(D_DIM / TILE_N, S_DIM / TILE_M, B_DIM);
  gemm_bt<false><<<gz, 256, 0, stream>>>(qb, kvT, zb, D_DIM, D_DIM, D_DIM, D_DIM,
                                         (long long)S_DIM * D_DIM, (long long)D_DIM * D_DIM,
                                         (long long)S_DIM * D_DIM, nullptr, nullptr);

  // ---- out = z @ Wp^T + bp + x : M=32768, N=1024, K=1024, fp32 out ----
  gemm_bt<true><<<gqkv, 256, 0, stream>>>(zb, Wpb, out, D_DIM, D_DIM, D_DIM, D_DIM,
                                          0, 0, 0, bp, x);
  (void)in_sizes; (void)n_in; (void)out_size; (void)ws_size;
}

// Round 3
// 726.401 us; speedup vs baseline: 1.3516x; 1.1123x over previous
//
#include <hip/hip_runtime.h>
#include <hip/hip_bf16.h>

// ---------------------------------------------------------------------------
// PLTBlock: out = (x Wq^T)( (x Wk^T)^T (x Wv^T) ) Wp^T + bp + x   (linear attn)
// B=8, S=4096, D=1024.  bf16 MFMA 16x16x32, fp32 accum.
// R3: force 3 waves/SIMD (3 blocks/CU) via __launch_bounds__(256,3) + reg
//     trims (arch VGPR must be <=~106 with 64 AGPR acc).  Coalesced epilogue
//     through LDS: 128-B-line stores kill the partial-line RMW that showed as
//     WRITE_SIZE 132MB / +64MB FETCH for a 64MB bf16 C.
// ---------------------------------------------------------------------------

#define B_DIM 8
#define S_DIM 4096
#define D_DIM 1024
#define M_TOT (B_DIM * S_DIM)   // 32768

using short8 = __attribute__((ext_vector_type(8))) short;
using f32x4  = __attribute__((ext_vector_type(4))) float;

#define TILE_M 128
#define TILE_N 128
#define TILE_K 64

__device__ __forceinline__ void g2l16(const void* g, void* l) {
  __builtin_amdgcn_global_load_lds(
      (const __attribute__((address_space(1))) unsigned int*)g,
      (__attribute__((address_space(3))) unsigned int*)l, 16, 0, 0);
}

__device__ __forceinline__ unsigned short f2b(float f) {
  __hip_bfloat16 h = __float2bfloat16(f);
  return __builtin_bit_cast(unsigned short, h);
}

// C[m,n] = sum_k A[m,k] * Bt[n,k]   (A: MxK row-major, Bt: NxK row-major)
// FINAL=false: C bf16.  FINAL=true: C fp32, += bias[n] + resid[m*ldc+n].
// LDS rotation: slot c of row r holds global 16B-chunk (c+r)&7 (conflict-free,
// keeps global_load_lds's wave-uniform-base+lane*16 destination).
template<bool FINAL>
__global__ __launch_bounds__(256, 3)   // 3 waves/EU: arch VGPR+64 AGPR <= 170
void gemm_bt(const unsigned short* __restrict__ A,
             const unsigned short* __restrict__ Bt,
             void* __restrict__ C,
             int K, int lda, int ldb, int ldc,
             long long sA, long long sB, long long sC,
             const float* __restrict__ bias,
             const float* __restrict__ resid)
{
  __shared__ __align__(16) unsigned short smem[TILE_M * TILE_K + TILE_N * TILE_K]; // 32 KiB
  unsigned short* As = smem;
  unsigned short* Bs = smem + TILE_M * TILE_K;

  const int tid  = threadIdx.x;
  const int wave = tid >> 6;
  const int lane = tid & 63;
  const int qd   = lane >> 4;
  const int ln   = lane & 15;
  const int wr   = (wave >> 1) * 64;
  const int wc   = (wave & 1) * 64;

  // XCD-stripe swizzle (xcd ~ flat%8 round-robin).
  const int flat = blockIdx.y * gridDim.x + blockIdx.x;
  const int strp = flat & 7;
  const int t8   = flat >> 3;
  const int bx   = t8 % gridDim.x;
  const int by   = strp * (gridDim.y >> 3) + t8 / gridDim.x;

  const long long m0 = (long long)by * TILE_M;
  const long long n0 = (long long)bx * TILE_N;
  const int bz = blockIdx.z;

  const unsigned short* Ab = A  + (long long)bz * sA;
  const unsigned short* Bb = Bt + (long long)bz * sB;

  // Staging: 128x64 bf16 = 16 KiB = 1024 16B-chunks; 256 thr x 4 iters.
  const int srow = tid >> 3;
  const int scg  = ((tid & 7) + (tid >> 3)) & 7;
  const unsigned short* pA = Ab + (m0 + srow) * lda + scg * 8;
  const unsigned short* pB = Bb + (n0 + srow) * ldb + scg * 8;
  const long long rsA = 32LL * lda, rsB = 32LL * ldb;
  unsigned short* lA = As + wave * 512;
  unsigned short* lB = Bs + wave * 512;

  // Fragment row bases + rotation seeds (16 regs; per-kk slot computed inline).
  int rowA[4], sA0[4], rowB[4], sB0[4];
#pragma unroll
  for (int i = 0; i < 4; ++i) {
    int ra = wr + i * 16 + ln;
    int rb = wc + i * 16 + ln;
    rowA[i] = ra * 64;  sA0[i] = (qd - ra) & 7;
    rowB[i] = rb * 64;  sB0[i] = (qd - rb) & 7;
  }

  f32x4 acc[4][4];
#pragma unroll
  for (int i = 0; i < 4; ++i)
#pragma unroll
    for (int j = 0; j < 4; ++j)
      acc[i][j] = (f32x4){0.f, 0.f, 0.f, 0.f};

  for (int k0 = 0; k0 < K; k0 += TILE_K) {
#pragma unroll
    for (int it = 0; it < 4; ++it) g2l16(pA + it * rsA, lA + it * 2048);
#pragma unroll
    for (int it = 0; it < 4; ++it) g2l16(pB + it * rsB, lB + it * 2048);
    __syncthreads();

#pragma unroll
    for (int kk = 0; kk < 2; ++kk) {
      short8 af[4], bf[4];
#pragma unroll
      for (int i = 0; i < 4; ++i)
        af[i] = *(const short8*)(As + rowA[i] + (((sA0[i] + kk * 4) & 7) << 3));
#pragma unroll
      for (int j = 0; j < 4; ++j)
        bf[j] = *(const short8*)(Bs + rowB[j] + (((sB0[j] + kk * 4) & 7) << 3));
#pragma unroll
      for (int i = 0; i < 4; ++i)
#pragma unroll
        for (int j = 0; j < 4; ++j)
          acc[i][j] = __builtin_amdgcn_mfma_f32_16x16x32_bf16(af[i], bf[j], acc[i][j], 0, 0, 0);
    }
    __syncthreads();
    pA += TILE_K; pB += TILE_K;
  }

  // ---- Coalesced epilogue: 4 passes of 32 rows via LDS (stride 132 fp32).
  // acc C/D layout (m89): col = lane&15, row-in-frag = qd*4 + reg.
  float* Ct = (float*)smem;   // 32*132*4 = 16896 B, fits in 32 KiB smem
  const int fr = tid >> 3;            // FINAL: row 0..31
  const int fc = (tid & 7) * 4;       // FINAL: col base; +s*32
  const int hr = tid >> 4;            // bf16: row 0..15 (+rs*16)
  const int hc = (tid & 15) * 4;      // bf16: col base; +s*64

#pragma unroll
  for (int p = 0; p < 4; ++p) {
    __syncthreads();
    if ((wr >> 6) == (p >> 1)) {
      const int ibase = (p & 1) * 2;
#pragma unroll
      for (int ii = 0; ii < 2; ++ii)
#pragma unroll
        for (int j = 0; j < 4; ++j)
#pragma unroll
          for (int r = 0; r < 4; ++r)
            Ct[(ii * 16 + qd * 4 + r) * 132 + wc + j * 16 + ln] = acc[ibase + ii][j][r];
    }
    __syncthreads();

    if constexpr (FINAL) {
      float* Cf = (float*)C + (long long)bz * sC;
      const long long grow = m0 + p * 32 + fr;
#pragma unroll
      for (int s = 0; s < 4; ++s) {
        const int c = fc + s * 32;
        float4 v = *(const float4*)(Ct + fr * 132 + c);
        const float4 bb = *(const float4*)(bias + n0 + c);
        const float4 rr = *(const float4*)(resid + grow * ldc + n0 + c);
        v.x += bb.x + rr.x; v.y += bb.y + rr.y;
        v.z += bb.z + rr.z; v.w += bb.w + rr.w;
        *(float4*)(Cf + grow * ldc + n0 + c) = v;
      }
    } else {
      unsigned short* Cb = (unsigned short*)C + (long long)bz * sC;
#pragma unroll
      for (int rs = 0; rs < 2; ++rs) {
        const int row = hr + rs * 16;
        const long long grow = m0 + p * 32 + row;
#pragma unroll
        for (int s = 0; s < 2; ++s) {
          const int c = hc + s * 64;
          float4 v = *(const float4*)(Ct + row * 132 + c);
          ushort4 u;
          u.x = f2b(v.x); u.y = f2b(v.y); u.z = f2b(v.z); u.w = f2b(v.w);
          *(ushort4*)(Cb + grow * ldc + n0 + c) = u;
        }
      }
    }
  }
}

// dst[b][e][s] = src[b*S + s][e]   (src: [B*S, D] bf16, dst: [B, D, S] bf16)
__global__ __launch_bounds__(256)
void transpose_bds(const unsigned short* __restrict__ src,
                   unsigned short* __restrict__ dst)
{
  __shared__ unsigned short tile[64][68];
  const int b  = blockIdx.z;
  const int s0 = blockIdx.x * 64;
  const int e0 = blockIdx.y * 64;
  const int tx = threadIdx.x & 15;
  const int ty = threadIdx.x >> 4;

#pragma unroll
  for (int r = 0; r < 4; ++r) {
    int s = ty * 4 + r;
    ushort4 d = *(const ushort4*)(src + ((size_t)b * S_DIM + s0 + s) * D_DIM + e0 + tx * 4);
    *(ushort4*)&tile[s][tx * 4] = d;
  }
  __syncthreads();
#pragma unroll
  for (int r = 0; r < 4; ++r) {
    int e = ty * 4 + r;
    ushort4 d;
    d.x = tile[tx * 4 + 0][e];
    d.y = tile[tx * 4 + 1][e];
    d.z = tile[tx * 4 + 2][e];
    d.w = tile[tx * 4 + 3][e];
    *(ushort4*)(dst + ((size_t)b * D_DIM + e0 + e) * S_DIM + s0 + tx * 4) = d;
  }
}

__global__ __launch_bounds__(256)
void cast_f32_bf16(const float* __restrict__ src, unsigned short* __restrict__ dst, int n4)
{
  int i = blockIdx.x * 256 + threadIdx.x;
  if (i >= n4) return;
  float4 f = ((const float4*)src)[i];
  ushort4 u;
  u.x = f2b(f.x); u.y = f2b(f.y); u.z = f2b(f.z); u.w = f2b(f.w);
  ((ushort4*)dst)[i] = u;
}

extern "C" void kernel_launch(void* const* d_in, const int* in_sizes, int n_in,
                              void* d_out, int out_size, void* d_ws, size_t ws_size,
                              hipStream_t stream) {
  const float* x  = (const float*)d_in[0];
  const float* Wq = (const float*)d_in[1];
  const float* Wk = (const float*)d_in[2];
  const float* Wv = (const float*)d_in[3];
  const float* Wp = (const float*)d_in[4];
  const float* bp = (const float*)d_in[5];
  float* out = (float*)d_out;
  char* ws = (char*)d_ws;

  unsigned short* xb  = (unsigned short*)(ws + 0);
  unsigned short* Wqb = (unsigned short*)(ws + 67108864);
  unsigned short* Wkb = (unsigned short*)(ws + 69206016);
  unsigned short* Wvb = (unsigned short*)(ws + 71303168);
  unsigned short* Wpb = (unsigned short*)(ws + 73400320);
  unsigned short* qb  = (unsigned short*)(ws + 75497472);
  unsigned short* kb  = (unsigned short*)(ws + 142606336);
  unsigned short* vb  = (unsigned short*)(ws + 209715200);
  unsigned short* kT  = (unsigned short*)(ws + 0);          // reuse xb
  unsigned short* vT  = (unsigned short*)(ws + 142606336);  // reuse kb
  unsigned short* kvT = (unsigned short*)(ws + 209715200);  // reuse vb
  unsigned short* zb  = (unsigned short*)(ws + 0);          // reuse kT

  // ---- casts to bf16 ----
  cast_f32_bf16<<<dim3(M_TOT * D_DIM / 4 / 256), 256, 0, stream>>>(x, xb, M_TOT * D_DIM / 4);
  cast_f32_bf16<<<dim3(D_DIM * D_DIM / 4 / 256), 256, 0, stream>>>(Wq, Wqb, D_DIM * D_DIM / 4);
  cast_f32_bf16<<<dim3(D_DIM * D_DIM / 4 / 256), 256, 0, stream>>>(Wk, Wkb, D_DIM * D_DIM / 4);
  cast_f32_bf16<<<dim3(D_DIM * D_DIM / 4 / 256), 256, 0, stream>>>(Wv, Wvb, D_DIM * D_DIM / 4);
  cast_f32_bf16<<<dim3(D_DIM * D_DIM / 4 / 256), 256, 0, stream>>>(Wp, Wpb, D_DIM * D_DIM / 4);

  // ---- q,k,v = x @ W^T : M=32768, N=1024, K=1024 ----
  dim3 gqkv(D_DIM / TILE_N, M_TOT / TILE_M, 1);
  gemm_bt<false><<<gqkv, 256, 0, stream>>>(xb, Wqb, qb, D_DIM, D_DIM, D_DIM, D_DIM, 0, 0, 0, nullptr, nullptr);
  gemm_bt<false><<<gqkv, 256, 0, stream>>>(xb, Wkb, kb, D_DIM, D_DIM, D_DIM, D_DIM, 0, 0, 0, nullptr, nullptr);
  gemm_bt<false><<<gqkv, 256, 0, stream>>>(xb, Wvb, vb, D_DIM, D_DIM, D_DIM, D_DIM, 0, 0, 0, nullptr, nullptr);

  // ---- kT[b][e][s], vT[b][f][s] ----
  dim3 gt(S_DIM / 64, D_DIM / 64, B_DIM);
  transpose_bds<<<gt, 256, 0, stream>>>(kb, kT);
  transpose_bds<<<gt, 256, 0, stream>>>(vb, vT);

  // ---- kvT[b][f][e] = sum_s vT[f,s] * kT[e,s] : M=N=1024, K=4096 ----
  dim3 gkv(D_DIM / TILE_N, D_DIM / TILE_M, B_DIM);
  gemm_bt<false><<<gkv, 256, 0, stream>>>(vT, kT, kvT, S_DIM, S_DIM, S_DIM, D_DIM,
                                          (long long)D_DIM * S_DIM, (long long)D_DIM * S_DIM,
                                          (long long)D_DIM * D_DIM, nullptr, nullptr);

  // ---- z[b][s][f] = sum_e q[s,e] * kvT[f,e] : M=4096, N=1024, K=1024 ----
  dim3 gz(D_DIM / TILE_N, S_DIM / TILE_M, B_DIM);
  gemm_bt<false><<<gz, 256, 0, stream>>>(qb, kvT, zb, D_DIM, D_DIM, D_DIM, D_DIM,
                                         (long long)S_DIM * D_DIM, (long long)D_DIM * D_DIM,
                                         (long long)S_DIM * D_DIM, nullptr, nullptr);

  // ---- out = z @ Wp^T + bp + x : M=32768, N=1024, K=1024, fp32 out ----
  gemm_bt<true><<<gqkv, 256, 0, stream>>>(zb, Wpb, out, D_DIM, D_DIM, D_DIM, D_DIM,
                                          0, 0, 0, bp, x);
  (void)in_sizes; (void)n_in; (void)out_size; (void)ws_size;
}